// Round 6
// baseline (196.549 us; speedup 1.0000x reference)
//
#include <hip/hip_runtime.h>
#include <stdint.h>

#define L2E 1.44269504088896340736f

typedef _Float16 half8 __attribute__((ext_vector_type(8)));
typedef float floatx4 __attribute__((ext_vector_type(4)));
typedef float floatx16 __attribute__((ext_vector_type(16)));

static __device__ __forceinline__ unsigned short f32_to_f16u(float f) {
  union { _Float16 h; unsigned short s; } cv; cv.h = (_Float16)f; return cv.s;
}
static __device__ __forceinline__ _Float16 f32h(float f) { return (_Float16)f; }

// ---------------------------------------------------------------------------
// Projection GEMM (round-4 structure + A-prefetch):
// outT[n][o] = sum_c X[c][n]*W[o][c] + b[o]; 64 output cols per block.
// z=0: q,k from depth -> qT,kT [b][n][32] fp16
// z=1..4: v quarter from rgb -> v [b][co][n] fp16 (LDS-transpose epilogue)
// W staged once in LDS (32 KB); 8 k-iters, no in-loop barriers.
// ---------------------------------------------------------------------------
__global__ __launch_bounds__(256, 5) void proj_kernel(
    const float* __restrict__ rgb,
    const float* __restrict__ depth,
    const float* __restrict__ Wq, const float* __restrict__ bq,
    const float* __restrict__ Wk, const float* __restrict__ bk,
    const float* __restrict__ Wv, const float* __restrict__ bv,
    unsigned short* __restrict__ qT,
    unsigned short* __restrict__ kT,
    unsigned short* __restrict__ v)
{
  __shared__ __align__(16) unsigned short sW[64 * 256];  // 32 KB fp16, swizzled

  const int n0 = blockIdx.x * 64;
  const int b  = blockIdx.y;
  const int z  = blockIdx.z;
  const int t  = threadIdx.x;
  const int w  = t >> 6;
  const int lane = t & 63;
  const int l15 = lane & 15;
  const int q4  = lane >> 4;
  const int n_row = n0 + 16 * w + l15;

  const float* X = (z == 0) ? depth : rgb;
  const float* xb = X + (size_t)b * 256 * 4096;
  const float* xrow = xb + n_row;
  const int colbase = (z == 0) ? 0 : (z - 1) * 64;

  // stage W [64 o][256 c] fp16, 16B-chunk swizzle by (og&7)
#pragma unroll
  for (int it = 0; it < 8; it++) {
    int L = it * 256 + t;
    int og = L >> 5;
    int phys = L & 31;
    int ci = phys ^ (og & 7);
    const float* wr;
    if (z == 0) wr = (og < 32) ? (Wq + (size_t)og * 256) : (Wk + (size_t)(og - 32) * 256);
    else        wr = Wv + (size_t)(colbase + og) * 256;
    float4 w0 = *(const float4*)(wr + ci * 8);
    float4 w1 = *(const float4*)(wr + ci * 8 + 4);
    half8 h;
    h[0] = f32h(w0.x); h[1] = f32h(w0.y); h[2] = f32h(w0.z); h[3] = f32h(w0.w);
    h[4] = f32h(w1.x); h[5] = f32h(w1.y); h[6] = f32h(w1.z); h[7] = f32h(w1.w);
    *(half8*)&sW[(size_t)L * 8] = h;
  }

  float bias[4];
#pragma unroll
  for (int ct = 0; ct < 4; ct++) {
    int og = ct * 16 + l15;
    if (z == 0) bias[ct] = (og < 32) ? bq[og] : bk[og - 32];
    else        bias[ct] = bv[colbase + og];
  }
  __syncthreads();

  floatx4 acc[4];
#pragma unroll
  for (int i = 0; i < 4; i++) acc[i] = (floatx4){0.f, 0.f, 0.f, 0.f};

  // prefetch A (ks=0) as raw floats
  float af[8];
#pragma unroll
  for (int j = 0; j < 8; j++) af[j] = xrow[(size_t)(q4 * 8 + j) * 4096];

#pragma unroll
  for (int ks = 0; ks < 8; ks++) {
    half8 a;
#pragma unroll
    for (int j = 0; j < 8; j++) a[j] = (_Float16)af[j];
    // prefetch next k-slice before consuming MFMAs
    if (ks < 7) {
#pragma unroll
      for (int j = 0; j < 8; j++)
        af[j] = xrow[(size_t)(ks * 32 + 32 + q4 * 8 + j) * 4096];
    }
    const int ci = ks * 4 + q4;
#pragma unroll
    for (int ct = 0; ct < 4; ct++) {
      int og = ct * 16 + l15;
      half8 bf = *(const half8*)&sW[og * 256 + ((ci ^ (og & 7)) * 8)];
      acc[ct] = __builtin_amdgcn_mfma_f32_16x16x32_f16(a, bf, acc[ct], 0, 0, 0);
    }
  }

  __syncthreads();  // sW reads done before reuse

  if (z == 0) {
#pragma unroll
    for (int ct = 0; ct < 4; ct++) {
      int og = ct * 16 + l15;
#pragma unroll
      for (int r = 0; r < 4; r++) {
        int n = n0 + 16 * w + q4 * 4 + r;
        unsigned short hv = f32_to_f16u(acc[ct][r] + bias[ct]);
        if (og < 32) qT[((size_t)b * 4096 + n) * 32 + og] = hv;
        else         kT[((size_t)b * 4096 + n) * 32 + (og - 32)] = hv;
      }
    }
  } else {
    unsigned short* tile = sW;  // [64 co][pitch 72]
#pragma unroll
    for (int ct = 0; ct < 4; ct++) {
#pragma unroll
      for (int r = 0; r < 4; r++) {
        int co_l = ct * 16 + l15;
        int nl = 16 * w + q4 * 4 + r;
        tile[co_l * 72 + nl] = f32_to_f16u(acc[ct][r] + bias[ct]);
      }
    }
    __syncthreads();
#pragma unroll
    for (int it = 0; it < 2; it++) {
      int co_l = it * 32 + (t >> 3);
      int ch = t & 7;
      int4 val = *(const int4*)&tile[co_l * 72 + ch * 8];
      *(int4*)&v[((size_t)b * 256 + colbase + co_l) * 4096 + n0 + ch * 8] = val;
    }
  }
}

// ---------------------------------------------------------------------------
// Flash attention, split-m + co-half split:
// block = (64 n, b, z) with z = chunk*2 + half; half covers 128 co.
// Per 32-m iter: K-frags direct from global; stage V-half [128co][32m] (8 KB);
// S (2 MFMA/wave) + exp2 -> shared P [64n][40]; PV per wave = 32-co slice,
// 4x mfma_32x32x16. 2048 blocks -> ~6 blocks/CU.
// ---------------------------------------------------------------------------
__global__ __launch_bounds__(256, 6) void attn_kernel(
    const unsigned short* __restrict__ qT,  // [b][n][32] fp16
    const unsigned short* __restrict__ kT,  // [b][m][32] fp16
    const unsigned short* __restrict__ v,   // [b][co][m] fp16
    unsigned short* __restrict__ Op,        // [chunk][b][co][n] fp16 unnormalized
    float* __restrict__ lW)                 // [chunk][b][n]
{
  __shared__ __align__(16) unsigned char smem[18432];     // epilogue [128][72] shorts
  unsigned short* sV = (unsigned short*)smem;             // [128 co][32 m] swizzled (8192 B)
  unsigned short* sP = (unsigned short*)(smem + 8192);    // [64 n][pitch 40] (5120 B)

  const int n0 = blockIdx.x * 64;
  const int b  = blockIdx.y;
  const int chunk = blockIdx.z >> 1;
  const int half  = blockIdx.z & 1;
  const int t  = threadIdx.x;
  const int w  = t >> 6;
  const int lane = t & 63;
  const int l15 = lane & 15;
  const int q4  = lane >> 4;
  const int l31 = lane & 31;
  const int hi  = lane >> 5;
  const int co0 = half * 128;

  const unsigned short* qrow = qT + ((size_t)b * 4096 + n0 + 16 * w + l15) * 32 + q4 * 8;
  half8 aq = *(const half8*)qrow;

  const unsigned short* vB = v  + (size_t)b * 256 * 4096 + (size_t)co0 * 4096;
  const unsigned short* kB = kT + (size_t)b * 4096 * 32;

  float lsum[4] = {0.f, 0.f, 0.f, 0.f};
  floatx16 acc[2];
#pragma unroll
  for (int nt = 0; nt < 2; nt++)
#pragma unroll
    for (int i = 0; i < 16; i++) acc[nt][i] = 0.f;
  const floatx4 zf = (floatx4){0.f, 0.f, 0.f, 0.f};

  const int mbase = chunk * 1024;
  for (int mi = 0; mi < 1024; mi += 32) {
    const int m0 = mbase + mi;
    // K-frags direct from global (2 KB tile, L2-hot across 128 blocks)
    half8 bk0 = *(const half8*)&kB[(size_t)(m0 + l15) * 32 + q4 * 8];
    half8 bk1 = *(const half8*)&kB[(size_t)(m0 + 16 + l15) * 32 + q4 * 8];

    __syncthreads();  // A: prev-iter sV/sP reads done
    // stage V-half [128 co][32 m]: phys chunk p holds logical p ^ ((c>>1)&3)
#pragma unroll
    for (int j = 0; j < 2; j++) {
      int lin = j * 256 + t;
      int c = lin >> 2;
      int p = lin & 3;
      int lc = p ^ ((c >> 1) & 3);
      uint4 val = *(const uint4*)&vB[(size_t)c * 4096 + m0 + lc * 8];
      *(uint4*)&sV[lin * 8] = val;
    }
    __syncthreads();  // B: sV visible (also orders sP overwrite below)

    // S phase: wave w computes rows 16w..16w+15
    floatx4 s0 = __builtin_amdgcn_mfma_f32_16x16x32_f16(aq, bk0, zf, 0, 0, 0);
    floatx4 s1 = __builtin_amdgcn_mfma_f32_16x16x32_f16(aq, bk1, zf, 0, 0, 0);

    float p0[4], p1[4];
#pragma unroll
    for (int r = 0; r < 4; r++) {
      p0[r] = exp2f(s0[r] * L2E);
      p1[r] = exp2f(s1[r] * L2E);
      lsum[r] += p0[r] + p1[r];
    }
#pragma unroll
    for (int r = 0; r < 4; r++) {
      int row = w * 16 + q4 * 4 + r;
      sP[row * 40 + l15]      = f32_to_f16u(p0[r]);
      sP[row * 40 + 16 + l15] = f32_to_f16u(p1[r]);
    }
    __syncthreads();  // C: P visible to all waves

    // PV phase: wave w covers local co = w*32..w*32+31, all 64 n
    const int c_lw = w * 32 + l31;
#pragma unroll
    for (int kst = 0; kst < 2; kst++) {
      int lc = (kst * 2 + hi) ^ ((c_lw >> 1) & 3);
      half8 bvv = *(const half8*)&sV[(c_lw * 4 + lc) * 8];
#pragma unroll
      for (int nt = 0; nt < 2; nt++) {
        half8 ap = *(const half8*)&sP[(nt * 32 + l31) * 40 + kst * 16 + hi * 8];
        acc[nt] = __builtin_amdgcn_mfma_f32_32x32x16_f16(ap, bvv, acc[nt], 0, 0, 0);
      }
    }
  }

  // l: reduce over the 16 lanes of each row group; only half 0 writes
#pragma unroll
  for (int off = 1; off < 16; off <<= 1) {
#pragma unroll
    for (int r = 0; r < 4; r++) lsum[r] += __shfl_xor(lsum[r], off);
  }
  if (half == 0 && l15 == 0) {
#pragma unroll
    for (int r = 0; r < 4; r++)
      lW[((size_t)chunk * 4 + b) * 4096 + n0 + 16 * w + q4 * 4 + r] = lsum[r];
  }

  // epilogue: [128 co][pitch 72] fp16 transpose, coalesced stores
  __syncthreads();
  unsigned short* sO = (unsigned short*)smem;
  const int co_l = w * 32 + l31;
#pragma unroll
  for (int nt = 0; nt < 2; nt++) {
#pragma unroll
    for (int g = 0; g < 4; g++) {
      int nl = nt * 32 + g * 8 + hi * 4;
      ushort4 pk;
      pk.x = f32_to_f16u(acc[nt][g * 4 + 0]);
      pk.y = f32_to_f16u(acc[nt][g * 4 + 1]);
      pk.z = f32_to_f16u(acc[nt][g * 4 + 2]);
      pk.w = f32_to_f16u(acc[nt][g * 4 + 3]);
      *(ushort4*)&sO[co_l * 72 + nl] = pk;
    }
  }
  __syncthreads();
#pragma unroll
  for (int s = 0; s < 4; s++) {
    int cl = s * 32 + (t >> 3);
    int ch = t & 7;
    int4 val = *(const int4*)&sO[cl * 72 + ch * 8];
    *(int4*)&Op[(((size_t)chunk * 4 + b) * 256 + co0 + cl) * 4096 + n0 + ch * 8] = val;
  }
}

// ---------------------------------------------------------------------------
// Combine: out[b][co][n] = sum_ch Op[ch][b][co][n] / sum_ch lW[ch][b][n]
// 2048 blocks: one co per block-z, 2048 n per block.
// ---------------------------------------------------------------------------
__global__ __launch_bounds__(256) void combine_kernel(
    const unsigned short* __restrict__ Op,
    const float* __restrict__ lW,
    float* __restrict__ out)
{
  const int t = threadIdx.x;
  const int b = blockIdx.y;
  const int co = blockIdx.z;
  const size_t n8 = (size_t)blockIdx.x * 2048 + (size_t)t * 8;

  float sum[8] = {0.f, 0.f, 0.f, 0.f, 0.f, 0.f, 0.f, 0.f};
  float o[8]   = {0.f, 0.f, 0.f, 0.f, 0.f, 0.f, 0.f, 0.f};
#pragma unroll
  for (int ch = 0; ch < 4; ch++) {
    const float* lp = lW + ((size_t)ch * 4 + b) * 4096 + n8;
    float4 a0 = *(const float4*)lp;
    float4 a1 = *(const float4*)(lp + 4);
    sum[0] += a0.x; sum[1] += a0.y; sum[2] += a0.z; sum[3] += a0.w;
    sum[4] += a1.x; sum[5] += a1.y; sum[6] += a1.z; sum[7] += a1.w;
    half8 hv = *(const half8*)&Op[(((size_t)ch * 4 + b) * 256 + co) * 4096 + n8];
#pragma unroll
    for (int i = 0; i < 8; i++) o[i] += (float)hv[i];
  }
  float* op = out + ((size_t)b * 256 + co) * 4096 + n8;
  float4 r0, r1;
  r0.x = o[0] / sum[0]; r0.y = o[1] / sum[1]; r0.z = o[2] / sum[2]; r0.w = o[3] / sum[3];
  r1.x = o[4] / sum[4]; r1.y = o[5] / sum[5]; r1.z = o[6] / sum[6]; r1.w = o[7] / sum[7];
  *(float4*)op = r0;
  *(float4*)(op + 4) = r1;
}

extern "C" void kernel_launch(void* const* d_in, const int* in_sizes, int n_in,
                              void* d_out, int out_size, void* d_ws, size_t ws_size,
                              hipStream_t stream) {
  const float* rgb   = (const float*)d_in[0];
  const float* depth = (const float*)d_in[1];
  const float* Wq    = (const float*)d_in[2];
  const float* bq    = (const float*)d_in[3];
  const float* Wk    = (const float*)d_in[4];
  const float* bk    = (const float*)d_in[5];
  const float* Wv    = (const float*)d_in[6];
  const float* bv    = (const float*)d_in[7];
  float* out = (float*)d_out;

  unsigned short* qT = (unsigned short*)d_ws;             // 1 MB
  unsigned short* kT = qT + (size_t)4 * 4096 * 32;        // 1 MB
  unsigned short* vW = kT + (size_t)4 * 4096 * 32;        // 8 MB
  unsigned short* Op = vW + (size_t)4 * 256 * 4096;       // 33.5 MB
  float* lW = (float*)(Op + (size_t)4 * 4 * 256 * 4096);  // 256 KB

  dim3 pg(64, 4, 5);
  proj_kernel<<<pg, 256, 0, stream>>>(rgb, depth, Wq, bq, Wk, bk, Wv, bv, qT, kT, vW);
  dim3 ag(64, 4, 8);
  attn_kernel<<<ag, 256, 0, stream>>>(qT, kT, vW, Op, lW);
  dim3 cg(2, 4, 256);
  combine_kernel<<<cg, 256, 0, stream>>>(Op, lW, out);
}